// Round 2
// baseline (523.199 us; speedup 1.0000x reference)
//
#include <hip/hip_runtime.h>
#include <math.h>

// ---------------------------------------------------------------------------
// SpatialDecoder: 3x { h = x @ W^T ; GAT edge softmax over dst ; mean ; ELU }
// NT = 32768 nodes, C = H = 256, E = 262144 edges.
// Strategy: counting-sort edges by dst once, then per layer:
//   gemm_xwT (f32 LDS-tiled) -> rowdots (s_i, s_j) -> aggregate (1 wave/node)
// ---------------------------------------------------------------------------

__global__ __launch_bounds__(256) void gemm_xwT(const float* __restrict__ X,
                                                const float* __restrict__ W,
                                                float* __restrict__ Hout)
{
    // Hout(M,256) = X(M,256) @ W(256,256)^T
    const int K = 256;
    __shared__ float As[16][68];   // [k][m], pad 68 to dodge write conflicts
    __shared__ float Bs[16][68];   // [k][n]
    const int tid = threadIdx.x;
    const int tx = tid & 15, ty = tid >> 4;
    const int m0 = blockIdx.x * 64;
    const int n0 = blockIdx.y * 64;
    const int lr = tid >> 2;          // 0..63 (row within tile)
    const int lc = (tid & 3) * 4;     // 0,4,8,12 (k offset within 16-wide K-tile)

    float acc[4][4] = {};
    const float* Xp = X + (size_t)(m0 + lr) * K + lc;
    const float* Wp = W + (size_t)(n0 + lr) * K + lc;

    for (int k0 = 0; k0 < K; k0 += 16) {
        float4 av = *(const float4*)(Xp + k0);
        float4 bv = *(const float4*)(Wp + k0);
        As[lc + 0][lr] = av.x; As[lc + 1][lr] = av.y;
        As[lc + 2][lr] = av.z; As[lc + 3][lr] = av.w;
        Bs[lc + 0][lr] = bv.x; Bs[lc + 1][lr] = bv.y;
        Bs[lc + 2][lr] = bv.z; Bs[lc + 3][lr] = bv.w;
        __syncthreads();
#pragma unroll
        for (int kk = 0; kk < 16; ++kk) {
            const float4 a4 = *(const float4*)&As[kk][ty * 4];
            const float4 b4 = *(const float4*)&Bs[kk][tx * 4];
            const float aa[4] = {a4.x, a4.y, a4.z, a4.w};
            const float bb[4] = {b4.x, b4.y, b4.z, b4.w};
#pragma unroll
            for (int i = 0; i < 4; ++i)
#pragma unroll
                for (int j = 0; j < 4; ++j)
                    acc[i][j] += aa[i] * bb[j];
        }
        __syncthreads();
    }
#pragma unroll
    for (int i = 0; i < 4; ++i) {
        float4 o = {acc[i][0], acc[i][1], acc[i][2], acc[i][3]};
        *(float4*)&Hout[(size_t)(m0 + ty * 4 + i) * 256 + n0 + tx * 4] = o;
    }
}

__global__ __launch_bounds__(256) void rowdots(const float* __restrict__ H,
                                               const float* __restrict__ a,
                                               float* __restrict__ si,
                                               float* __restrict__ sj,
                                               int n_nodes)
{
    const int wave = (blockIdx.x * 256 + threadIdx.x) >> 6;
    const int lane = threadIdx.x & 63;
    if (wave >= n_nodes) return;
    const float4 alo = *(const float4*)&a[lane * 4];
    const float4 ahi = *(const float4*)&a[256 + lane * 4];
    const float4 hv  = *(const float4*)&H[(size_t)wave * 256 + lane * 4];
    float d0 = hv.x * alo.x + hv.y * alo.y + hv.z * alo.z + hv.w * alo.w;
    float d1 = hv.x * ahi.x + hv.y * ahi.y + hv.z * ahi.z + hv.w * ahi.w;
#pragma unroll
    for (int d = 32; d; d >>= 1) {
        d0 += __shfl_xor(d0, d);
        d1 += __shfl_xor(d1, d);
    }
    if (lane == 0) { si[wave] = d0; sj[wave] = d1; }
}

// ------------------------- edge preprocessing ------------------------------

__global__ void zero_int(int* p, int n)
{
    int i = blockIdx.x * blockDim.x + threadIdx.x;
    if (i < n) p[i] = 0;
}

__global__ void hist_kernel(const int* __restrict__ dst, int* __restrict__ cnt, int E)
{
    int e = blockIdx.x * blockDim.x + threadIdx.x;
    if (e < E) atomicAdd(&cnt[dst[e]], 1);
}

__global__ __launch_bounds__(1024) void scan_off(const int* __restrict__ cnt,
                                                 int* __restrict__ off,
                                                 int* __restrict__ cursor,
                                                 int n)
{
    __shared__ int buf[1024];
    __shared__ int s_carry;
    const int tid = threadIdx.x;
    if (tid == 0) s_carry = 0;
    __syncthreads();
    for (int base = 0; base < n; base += 1024) {
        int v = cnt[base + tid];
        buf[tid] = v;
        __syncthreads();
#pragma unroll
        for (int d = 1; d < 1024; d <<= 1) {
            int t = (tid >= d) ? buf[tid - d] : 0;
            __syncthreads();
            buf[tid] += t;
            __syncthreads();
        }
        int incl = buf[tid] + s_carry;
        int excl = incl - v;
        off[base + tid]    = excl;
        cursor[base + tid] = excl;
        __syncthreads();
        if (tid == 1023) s_carry = incl;
        __syncthreads();
    }
    if (tid == 1023) off[n] = s_carry;
}

__global__ void scatter_kernel(const int* __restrict__ src,
                               const int* __restrict__ dst,
                               int* __restrict__ cursor,
                               int* __restrict__ ssrc, int E)
{
    int e = blockIdx.x * blockDim.x + threadIdx.x;
    if (e < E) {
        int p = atomicAdd(&cursor[dst[e]], 1);
        ssrc[p] = src[e];
    }
}

// ------------------------- per-node softmax + aggregate --------------------

__global__ __launch_bounds__(256) void aggregate(const float* __restrict__ H,
                                                 const float* __restrict__ si,
                                                 const float* __restrict__ sj,
                                                 const int* __restrict__ off,
                                                 const int* __restrict__ ssrc,
                                                 float* __restrict__ out,
                                                 int n_nodes)
{
    const int v = (blockIdx.x * 256 + threadIdx.x) >> 6;   // one wave per node
    const int lane = threadIdx.x & 63;
    if (v >= n_nodes) return;

    const int e0 = off[v], e1 = off[v + 1];
    const int deg = e1 - e0;
    float4 acc = {0.f, 0.f, 0.f, 0.f};

    if (deg > 0) {
        const float siv = si[v];
        // pass 1: segment max of leaky_relu(score)
        float m = -1e30f;
        for (int b = e0 + lane; b < e1; b += 64) {
            float s = siv + sj[ssrc[b]];
            s = (s >= 0.f) ? s : 0.2f * s;
            m = fmaxf(m, s);
        }
#pragma unroll
        for (int d = 32; d; d >>= 1) m = fmaxf(m, __shfl_xor(m, d));
        // pass 1b: denom
        float den = 0.f;
        for (int b = e0 + lane; b < e1; b += 64) {
            float s = siv + sj[ssrc[b]];
            s = (s >= 0.f) ? s : 0.2f * s;
            den += __expf(s - m);
        }
#pragma unroll
        for (int d = 32; d; d >>= 1) den += __shfl_xor(den, d);
        // pass 2: weighted gather of h[src] rows (1KB coalesced per edge)
        for (int e = e0; e < e1; ++e) {
            const int s = ssrc[e];
            float sc = siv + sj[s];
            sc = (sc >= 0.f) ? sc : 0.2f * sc;
            const float w = __expf(sc - m);
            const float4 hv = *(const float4*)&H[(size_t)s * 256 + lane * 4];
            acc.x += w * hv.x; acc.y += w * hv.y;
            acc.z += w * hv.z; acc.w += w * hv.w;
        }
        const float inv = 1.f / (den * (float)deg);
        acc.x *= inv; acc.y *= inv; acc.z *= inv; acc.w *= inv;
    }
    // ELU
    float4 o;
    o.x = (acc.x > 0.f) ? acc.x : (__expf(acc.x) - 1.f);
    o.y = (acc.y > 0.f) ? acc.y : (__expf(acc.y) - 1.f);
    o.z = (acc.z > 0.f) ? acc.z : (__expf(acc.z) - 1.f);
    o.w = (acc.w > 0.f) ? acc.w : (__expf(acc.w) - 1.f);
    *(float4*)&out[(size_t)v * 256 + lane * 4] = o;
}

// ---------------------------------------------------------------------------

extern "C" void kernel_launch(void* const* d_in, const int* in_sizes, int n_in,
                              void* d_out, int out_size, void* d_ws, size_t ws_size,
                              hipStream_t stream)
{
    const float* x0 = (const float*)d_in[0];
    const int*   ei = (const int*)d_in[1];      // (2,E) int32: row0=src, row1=dst
    const float* Ws[3] = {(const float*)d_in[2], (const float*)d_in[4], (const float*)d_in[6]};
    const float* as[3] = {(const float*)d_in[3], (const float*)d_in[5], (const float*)d_in[7]};
    float* out = (float*)d_out;

    const int NT = in_sizes[0] / 256;   // 32768
    const int E  = in_sizes[1] / 2;     // 262144
    const int* srcI = ei;
    const int* dstI = ei + E;

    // workspace layout (~66 MB)
    float* h   = (float*)d_ws;
    float* x1  = h  + (size_t)NT * 256;
    float* si  = x1 + (size_t)NT * 256;
    float* sj  = si + NT;
    int* cnt    = (int*)(sj + NT);
    int* off    = cnt + NT;          // NT+1 entries
    int* cursor = off + NT + 1;
    int* ssrc   = cursor + NT;       // E entries

    // edge preprocessing (layer-invariant)
    zero_int<<<(NT + 255) / 256, 256, 0, stream>>>(cnt, NT);
    hist_kernel<<<(E + 255) / 256, 256, 0, stream>>>(dstI, cnt, E);
    scan_off<<<1, 1024, 0, stream>>>(cnt, off, cursor, NT);
    scatter_kernel<<<(E + 255) / 256, 256, 0, stream>>>(srcI, dstI, cursor, ssrc, E);

    const float* xin = x0;
    for (int l = 0; l < 3; ++l) {
        float* xout = (l == 2) ? out : x1;
        gemm_xwT<<<dim3(NT / 64, 4), 256, 0, stream>>>(xin, Ws[l], h);
        rowdots<<<NT / 4, 256, 0, stream>>>(h, as[l], si, sj, NT);
        aggregate<<<NT / 4, 256, 0, stream>>>(h, si, sj, off, ssrc, xout, NT);
        xin = x1;   // aggregate never reads x1, so in-place across layers is safe
    }
}

// Round 3
// 328.048 us; speedup vs baseline: 1.5949x; 1.5949x over previous
//
#include <hip/hip_runtime.h>
#include <math.h>
#include <stdint.h>

// ---------------------------------------------------------------------------
// SpatialDecoder: 3x { h = x @ W^T ; GAT edge softmax over dst ; mean ; ELU }
// NT = 32768 nodes, C = H = 256, E = 262144 edges.
// This round: fp16 MFMA GEMM (fused si/sj row-dots), hierarchical scan.
// ---------------------------------------------------------------------------

typedef float f32x4 __attribute__((ext_vector_type(4)));
typedef _Float16 f16x8 __attribute__((ext_vector_type(8)));
typedef _Float16 f16x4 __attribute__((ext_vector_type(4)));

#define LDSPAD 40   // f16 elements per LDS row slot (80B, 16B-aligned, 2-way max)

// ------------------------- W f32 -> f16 conversion -------------------------

__global__ __launch_bounds__(256) void convert_w_f16(const float* __restrict__ W,
                                                     _Float16* __restrict__ Wh)
{
    const int i = (blockIdx.x * 256 + threadIdx.x) * 4;
    float4 v = *(const float4*)&W[i];
    f16x4 o = {(_Float16)v.x, (_Float16)v.y, (_Float16)v.z, (_Float16)v.w};
    *(f16x4*)&Wh[i] = o;
}

// ------------------------- fp16 MFMA GEMM + row dots -----------------------
// Hout(M,256) = X(M,256) @ Wh(256,256)^T ; si = Hout@a[:256], sj = Hout@a[256:]

__global__ __launch_bounds__(256) void gemm_f16(const float* __restrict__ X,
                                                const _Float16* __restrict__ Wh,
                                                const float* __restrict__ avec,
                                                float* __restrict__ Hout,
                                                float* __restrict__ si,
                                                float* __restrict__ sj)
{
    __shared__ __align__(16) unsigned char smem[64 * LDSPAD * 2 + 256 * LDSPAD * 2];
    _Float16* Xs = (_Float16*)smem;                         // [64][LDSPAD]
    _Float16* Wl = (_Float16*)(smem + 64 * LDSPAD * 2);     // [256][LDSPAD]
    float*    Es = (float*)smem;                            // epilogue [16][260]

    const int tid  = threadIdx.x;
    const int lane = tid & 63;
    const int w    = tid >> 6;        // wave id = n-chunk (64 cols each)
    const int ln   = lane & 15;
    const int kq   = lane >> 4;
    const int m0   = blockIdx.x * 64;

    f32x4 acc[4][4] = {};

    const int sr = tid >> 2;          // X staging row 0..63
    const int sc = tid & 3;           // X staging chunk 0..3
    const float*    Xrow = X  + (size_t)(m0 + sr) * 256;
    const _Float16* Wrow = Wh + (size_t)tid * 256;

    for (int k0 = 0; k0 < 256; k0 += 32) {
        // stage X tile (64x32 f32 -> f16)
        float4 xa = *(const float4*)&Xrow[k0 + sc * 4];
        float4 xb = *(const float4*)&Xrow[k0 + 16 + sc * 4];
        f16x4 ha = {(_Float16)xa.x, (_Float16)xa.y, (_Float16)xa.z, (_Float16)xa.w};
        f16x4 hb = {(_Float16)xb.x, (_Float16)xb.y, (_Float16)xb.z, (_Float16)xb.w};
        *(f16x4*)&Xs[sr * LDSPAD + sc * 4]      = ha;
        *(f16x4*)&Xs[sr * LDSPAD + 16 + sc * 4] = hb;
        // stage W tile (256x32 f16, already converted)
        f16x8 w0 = *(const f16x8*)&Wrow[k0 + 0];
        f16x8 w1 = *(const f16x8*)&Wrow[k0 + 8];
        f16x8 w2 = *(const f16x8*)&Wrow[k0 + 16];
        f16x8 w3 = *(const f16x8*)&Wrow[k0 + 24];
        *(f16x8*)&Wl[tid * LDSPAD + 0]  = w0;
        *(f16x8*)&Wl[tid * LDSPAD + 8]  = w1;
        *(f16x8*)&Wl[tid * LDSPAD + 16] = w2;
        *(f16x8*)&Wl[tid * LDSPAD + 24] = w3;
        __syncthreads();

        f16x8 af[4], bf[4];
#pragma unroll
        for (int i = 0; i < 4; ++i)
            af[i] = *(const f16x8*)&Xs[(i * 16 + ln) * LDSPAD + kq * 8];
#pragma unroll
        for (int j = 0; j < 4; ++j)
            bf[j] = *(const f16x8*)&Wl[(w * 64 + j * 16 + ln) * LDSPAD + kq * 8];
#pragma unroll
        for (int i = 0; i < 4; ++i)
#pragma unroll
            for (int j = 0; j < 4; ++j)
                acc[i][j] = __builtin_amdgcn_mfma_f32_16x16x32_f16(af[i], bf[j], acc[i][j], 0, 0, 0);
        __syncthreads();
    }

    // Epilogue: LDS-transpose per 16-row group, coalesced store + fused dots.
    const int er = tid >> 4;          // row in 16-group
    const int ec = tid & 15;          // col-quad index
    for (int i = 0; i < 4; ++i) {
        // scatter acc fragments: C row = kq*4+q, col = w*64 + j*16 + ln
#pragma unroll
        for (int j = 0; j < 4; ++j) {
            const int col = w * 64 + j * 16 + ln;
#pragma unroll
            for (int q = 0; q < 4; ++q)
                Es[(kq * 4 + q) * 260 + col] = acc[i][j][q];
        }
        __syncthreads();
        const int grow = m0 + i * 16 + er;
        float d0 = 0.f, d1 = 0.f;
#pragma unroll
        for (int c4 = 0; c4 < 4; ++c4) {
            const int col = ec * 4 + c4 * 64;
            f32x4 v  = *(const f32x4*)&Es[er * 260 + col];
            *(f32x4*)&Hout[(size_t)grow * 256 + col] = v;
            f32x4 al = *(const f32x4*)&avec[col];
            f32x4 ah = *(const f32x4*)&avec[256 + col];
            d0 += v[0] * al[0] + v[1] * al[1] + v[2] * al[2] + v[3] * al[3];
            d1 += v[0] * ah[0] + v[1] * ah[1] + v[2] * ah[2] + v[3] * ah[3];
        }
#pragma unroll
        for (int d = 8; d; d >>= 1) {
            d0 += __shfl_xor(d0, d);
            d1 += __shfl_xor(d1, d);
        }
        if (ec == 0) { si[grow] = d0; sj[grow] = d1; }
        __syncthreads();
    }
}

// ------------------------- edge preprocessing ------------------------------

__global__ void zero_int(int* p, int n)
{
    int i = blockIdx.x * blockDim.x + threadIdx.x;
    if (i < n) p[i] = 0;
}

__global__ void hist_kernel(const int* __restrict__ dst, int* __restrict__ cnt, int E)
{
    int e = blockIdx.x * blockDim.x + threadIdx.x;
    if (e < E) atomicAdd(&cnt[dst[e]], 1);
}

__global__ __launch_bounds__(1024) void scan_part(const int* __restrict__ cnt,
                                                  int* __restrict__ off,
                                                  int* __restrict__ bsum)
{
    __shared__ int buf[1024];
    const int tid = threadIdx.x;
    const int g = blockIdx.x * 1024 + tid;
    int v = cnt[g];
    buf[tid] = v;
    __syncthreads();
#pragma unroll
    for (int d = 1; d < 1024; d <<= 1) {
        int t = (tid >= d) ? buf[tid - d] : 0;
        __syncthreads();
        buf[tid] += t;
        __syncthreads();
    }
    off[g] = buf[tid] - v;                      // local exclusive
    if (tid == 1023) bsum[blockIdx.x] = buf[1023];
}

__global__ void scan_bsum(int* bsum, int nb)
{
    __shared__ int b[64];
    const int tid = threadIdx.x;                // 64 threads
    b[tid] = (tid < nb) ? bsum[tid] : 0;
    __syncthreads();
    if (tid == 0) {
        int a = 0;
        for (int i = 0; i < nb; ++i) { int t = b[i]; b[i] = a; a += t; }
    }
    __syncthreads();
    if (tid < nb) bsum[tid] = b[tid];
}

__global__ __launch_bounds__(1024) void scan_add(const int* __restrict__ bsum,
                                                 int* __restrict__ off,
                                                 int* __restrict__ cursor,
                                                 int NT, int E)
{
    const int tid = threadIdx.x;
    const int g = blockIdx.x * 1024 + tid;
    int v = off[g] + bsum[blockIdx.x];
    off[g] = v;
    cursor[g] = v;
    if (g == 0) off[NT] = E;
}

__global__ void scatter_kernel(const int* __restrict__ src,
                               const int* __restrict__ dst,
                               int* __restrict__ cursor,
                               int* __restrict__ ssrc, int E)
{
    int e = blockIdx.x * blockDim.x + threadIdx.x;
    if (e < E) {
        int p = atomicAdd(&cursor[dst[e]], 1);
        ssrc[p] = src[e];
    }
}

// ------------------------- per-node softmax + aggregate --------------------

__global__ __launch_bounds__(256) void aggregate(const float* __restrict__ H,
                                                 const float* __restrict__ si,
                                                 const float* __restrict__ sj,
                                                 const int* __restrict__ off,
                                                 const int* __restrict__ ssrc,
                                                 float* __restrict__ out,
                                                 int n_nodes)
{
    const int v = (blockIdx.x * 256 + threadIdx.x) >> 6;   // one wave per node
    const int lane = threadIdx.x & 63;
    if (v >= n_nodes) return;

    const int e0 = off[v], e1 = off[v + 1];
    const int deg = e1 - e0;
    float4 acc = {0.f, 0.f, 0.f, 0.f};

    if (deg > 0) {
        const float siv = si[v];
        float m = -1e30f;
        for (int b = e0 + lane; b < e1; b += 64) {
            float s = siv + sj[ssrc[b]];
            s = (s >= 0.f) ? s : 0.2f * s;
            m = fmaxf(m, s);
        }
#pragma unroll
        for (int d = 32; d; d >>= 1) m = fmaxf(m, __shfl_xor(m, d));
        float den = 0.f;
        for (int b = e0 + lane; b < e1; b += 64) {
            float s = siv + sj[ssrc[b]];
            s = (s >= 0.f) ? s : 0.2f * s;
            den += __expf(s - m);
        }
#pragma unroll
        for (int d = 32; d; d >>= 1) den += __shfl_xor(den, d);
        for (int e = e0; e < e1; ++e) {
            const int s = ssrc[e];
            float sc = siv + sj[s];
            sc = (sc >= 0.f) ? sc : 0.2f * sc;
            const float wgt = __expf(sc - m);
            const float4 hv = *(const float4*)&H[(size_t)s * 256 + lane * 4];
            acc.x += wgt * hv.x; acc.y += wgt * hv.y;
            acc.z += wgt * hv.z; acc.w += wgt * hv.w;
        }
        const float inv = 1.f / (den * (float)deg);
        acc.x *= inv; acc.y *= inv; acc.z *= inv; acc.w *= inv;
    }
    float4 o;
    o.x = (acc.x > 0.f) ? acc.x : (__expf(acc.x) - 1.f);
    o.y = (acc.y > 0.f) ? acc.y : (__expf(acc.y) - 1.f);
    o.z = (acc.z > 0.f) ? acc.z : (__expf(acc.z) - 1.f);
    o.w = (acc.w > 0.f) ? acc.w : (__expf(acc.w) - 1.f);
    *(float4*)&out[(size_t)v * 256 + lane * 4] = o;
}

// ---------------------------------------------------------------------------

extern "C" void kernel_launch(void* const* d_in, const int* in_sizes, int n_in,
                              void* d_out, int out_size, void* d_ws, size_t ws_size,
                              hipStream_t stream)
{
    const float* x0 = (const float*)d_in[0];
    const int*   ei = (const int*)d_in[1];      // (2,E) int32: row0=src, row1=dst
    const float* Ws[3] = {(const float*)d_in[2], (const float*)d_in[4], (const float*)d_in[6]};
    const float* as[3] = {(const float*)d_in[3], (const float*)d_in[5], (const float*)d_in[7]};
    float* out = (float*)d_out;

    const int NT = in_sizes[0] / 256;   // 32768
    const int E  = in_sizes[1] / 2;     // 262144
    const int* srcI = ei;
    const int* dstI = ei + E;

    // workspace layout
    float* h    = (float*)d_ws;
    float* x1   = h  + (size_t)NT * 256;
    float* si   = x1 + (size_t)NT * 256;
    float* sj   = si + NT;
    int* cnt    = (int*)(sj + NT);
    int* off    = cnt + NT;             // NT+1 entries
    int* cursor = off + NT + 1;
    int* ssrc   = cursor + NT;          // E entries
    int* bsum   = ssrc + E;             // 64 entries
    _Float16* Wh = (_Float16*)(((uintptr_t)(bsum + 64) + 255) & ~(uintptr_t)255);

    // weight conversion (f32 -> f16), 3 x 65536 elements
    for (int l = 0; l < 3; ++l)
        convert_w_f16<<<64, 256, 0, stream>>>(Ws[l], Wh + (size_t)l * 65536);

    // edge preprocessing (layer-invariant)
    zero_int<<<(NT + 255) / 256, 256, 0, stream>>>(cnt, NT);
    hist_kernel<<<(E + 255) / 256, 256, 0, stream>>>(dstI, cnt, E);
    scan_part<<<NT / 1024, 1024, 0, stream>>>(cnt, off, bsum);
    scan_bsum<<<1, 64, 0, stream>>>(bsum, NT / 1024);
    scan_add<<<NT / 1024, 1024, 0, stream>>>(bsum, off, cursor, NT, E);
    scatter_kernel<<<(E + 255) / 256, 256, 0, stream>>>(srcI, dstI, cursor, ssrc, E);

    const float* xin = x0;
    for (int l = 0; l < 3; ++l) {
        float* xout = (l == 2) ? out : x1;
        gemm_f16<<<NT / 64, 256, 0, stream>>>(xin, Wh + (size_t)l * 65536, as[l], h, si, sj);
        aggregate<<<NT / 4, 256, 0, stream>>>(h, si, sj, off, ssrc, xout, NT);
        xin = x1;   // aggregate never reads x1, so in-place across layers is safe
    }
}

// Round 5
// 324.594 us; speedup vs baseline: 1.6119x; 1.0106x over previous
//
#include <hip/hip_runtime.h>
#include <math.h>
#include <stdint.h>

// ---------------------------------------------------------------------------
// SpatialDecoder: 3x { h = x @ W^T ; GAT edge softmax over dst ; mean ; ELU }
// NT = 32768 nodes, C = H = 256, E = 262144 edges.
// This round: all intermediates (h, inter-layer x) in f16 — bit-identical to
// previous round's math (inputs were rounded to f16 in staging anyway) but
// halves GEMM read/write and the aggregate's random-gather traffic.
// ---------------------------------------------------------------------------

typedef float f32x4 __attribute__((ext_vector_type(4)));
typedef _Float16 f16x8 __attribute__((ext_vector_type(8)));
typedef _Float16 f16x4 __attribute__((ext_vector_type(4)));

#define LDSPAD 40   // f16 elements per LDS row slot (80B, 16B-aligned, <=2-way)

// ------------------------- f32 -> f16 conversion ---------------------------

__global__ __launch_bounds__(256) void convert_f16(const float* __restrict__ src,
                                                   _Float16* __restrict__ dstp)
{
    const int i = (blockIdx.x * 256 + threadIdx.x) * 8;
    float4 a = *(const float4*)&src[i];
    float4 b = *(const float4*)&src[i + 4];
    f16x8 o = {(_Float16)a.x, (_Float16)a.y, (_Float16)a.z, (_Float16)a.w,
               (_Float16)b.x, (_Float16)b.y, (_Float16)b.z, (_Float16)b.w};
    *(f16x8*)&dstp[i] = o;
}

// ------------------------- fp16 MFMA GEMM + row dots -----------------------
// Hout(M,256) = X(M,256) @ Wh(256,256)^T ; si = Hout@a[:256], sj = Hout@a[256:]

__global__ __launch_bounds__(256) void gemm_f16(const _Float16* __restrict__ X,
                                                const _Float16* __restrict__ Wh,
                                                const float* __restrict__ avec,
                                                _Float16* __restrict__ Hout,
                                                float* __restrict__ si,
                                                float* __restrict__ sj)
{
    __shared__ __align__(16) unsigned char smem[64 * LDSPAD * 2 + 256 * LDSPAD * 2];
    _Float16* Xs = (_Float16*)smem;                         // [64][LDSPAD]
    _Float16* Wl = (_Float16*)(smem + 64 * LDSPAD * 2);     // [256][LDSPAD]
    float*    Es = (float*)smem;                            // epilogue [16][260]

    const int tid  = threadIdx.x;
    const int lane = tid & 63;
    const int w    = tid >> 6;        // wave id = n-chunk (64 cols each)
    const int ln   = lane & 15;
    const int kq   = lane >> 4;
    const int m0   = blockIdx.x * 64;

    f32x4 acc[4][4] = {};

    const int sr = tid >> 2;          // X staging row 0..63
    const int sc = tid & 3;           // X staging chunk (8 f16 each)
    const _Float16* Xrow = X  + (size_t)(m0 + sr) * 256;
    const _Float16* Wrow = Wh + (size_t)tid * 256;

    for (int k0 = 0; k0 < 256; k0 += 32) {
        // stage X tile (64x32 f16) — one 16B copy per thread
        f16x8 xv = *(const f16x8*)&Xrow[k0 + sc * 8];
        *(f16x8*)&Xs[sr * LDSPAD + sc * 8] = xv;
        // stage W tile (256x32 f16)
        f16x8 w0 = *(const f16x8*)&Wrow[k0 + 0];
        f16x8 w1 = *(const f16x8*)&Wrow[k0 + 8];
        f16x8 w2 = *(const f16x8*)&Wrow[k0 + 16];
        f16x8 w3 = *(const f16x8*)&Wrow[k0 + 24];
        *(f16x8*)&Wl[tid * LDSPAD + 0]  = w0;
        *(f16x8*)&Wl[tid * LDSPAD + 8]  = w1;
        *(f16x8*)&Wl[tid * LDSPAD + 16] = w2;
        *(f16x8*)&Wl[tid * LDSPAD + 24] = w3;
        __syncthreads();

        f16x8 af[4], bf[4];
#pragma unroll
        for (int i = 0; i < 4; ++i)
            af[i] = *(const f16x8*)&Xs[(i * 16 + ln) * LDSPAD + kq * 8];
#pragma unroll
        for (int j = 0; j < 4; ++j)
            bf[j] = *(const f16x8*)&Wl[(w * 64 + j * 16 + ln) * LDSPAD + kq * 8];
#pragma unroll
        for (int i = 0; i < 4; ++i)
#pragma unroll
            for (int j = 0; j < 4; ++j)
                acc[i][j] = __builtin_amdgcn_mfma_f32_16x16x32_f16(af[i], bf[j], acc[i][j], 0, 0, 0);
        __syncthreads();
    }

    // Epilogue: LDS-transpose per 16-row group, coalesced f16 store + fused dots.
    const int er = tid >> 4;          // row in 16-group
    const int ec = tid & 15;          // col-quad index
    for (int i = 0; i < 4; ++i) {
#pragma unroll
        for (int j = 0; j < 4; ++j) {
            const int col = w * 64 + j * 16 + ln;
#pragma unroll
            for (int q = 0; q < 4; ++q)
                Es[(kq * 4 + q) * 260 + col] = acc[i][j][q];
        }
        __syncthreads();
        const int grow = m0 + i * 16 + er;
        float d0 = 0.f, d1 = 0.f;
#pragma unroll
        for (int c4 = 0; c4 < 4; ++c4) {
            const int col = ec * 4 + c4 * 64;
            f32x4 v  = *(const f32x4*)&Es[er * 260 + col];
            f16x4 hv = {(_Float16)v[0], (_Float16)v[1], (_Float16)v[2], (_Float16)v[3]};
            *(f16x4*)&Hout[(size_t)grow * 256 + col] = hv;
            f32x4 al = *(const f32x4*)&avec[col];
            f32x4 ah = *(const f32x4*)&avec[256 + col];
            d0 += v[0] * al[0] + v[1] * al[1] + v[2] * al[2] + v[3] * al[3];
            d1 += v[0] * ah[0] + v[1] * ah[1] + v[2] * ah[2] + v[3] * ah[3];
        }
#pragma unroll
        for (int d = 8; d; d >>= 1) {
            d0 += __shfl_xor(d0, d);
            d1 += __shfl_xor(d1, d);
        }
        if (ec == 0) { si[grow] = d0; sj[grow] = d1; }
        __syncthreads();
    }
}

// ------------------------- edge preprocessing ------------------------------

__global__ void zero_int(int* p, int n)
{
    int i = blockIdx.x * blockDim.x + threadIdx.x;
    if (i < n) p[i] = 0;
}

__global__ void hist_kernel(const int* __restrict__ dst, int* __restrict__ cnt, int E)
{
    int e = blockIdx.x * blockDim.x + threadIdx.x;
    if (e < E) atomicAdd(&cnt[dst[e]], 1);
}

__global__ __launch_bounds__(1024) void scan_part(const int* __restrict__ cnt,
                                                  int* __restrict__ off,
                                                  int* __restrict__ bsum)
{
    __shared__ int buf[1024];
    const int tid = threadIdx.x;
    const int g = blockIdx.x * 1024 + tid;
    int v = cnt[g];
    buf[tid] = v;
    __syncthreads();
#pragma unroll
    for (int d = 1; d < 1024; d <<= 1) {
        int t = (tid >= d) ? buf[tid - d] : 0;
        __syncthreads();
        buf[tid] += t;
        __syncthreads();
    }
    off[g] = buf[tid] - v;                      // local exclusive
    if (tid == 1023) bsum[blockIdx.x] = buf[1023];
}

__global__ void scan_bsum(int* bsum, int nb)
{
    __shared__ int b[64];
    const int tid = threadIdx.x;                // 64 threads
    b[tid] = (tid < nb) ? bsum[tid] : 0;
    __syncthreads();
    if (tid == 0) {
        int a = 0;
        for (int i = 0; i < nb; ++i) { int t = b[i]; b[i] = a; a += t; }
    }
    __syncthreads();
    if (tid < nb) bsum[tid] = b[tid];
}

__global__ __launch_bounds__(1024) void scan_add(const int* __restrict__ bsum,
                                                 int* __restrict__ off,
                                                 int* __restrict__ cursor,
                                                 int NT, int E)
{
    const int tid = threadIdx.x;
    const int g = blockIdx.x * 1024 + tid;
    int v = off[g] + bsum[blockIdx.x];
    off[g] = v;
    cursor[g] = v;
    if (g == 0) off[NT] = E;
}

__global__ void scatter_kernel(const int* __restrict__ src,
                               const int* __restrict__ dst,
                               int* __restrict__ cursor,
                               int* __restrict__ ssrc, int E)
{
    int e = blockIdx.x * blockDim.x + threadIdx.x;
    if (e < E) {
        int p = atomicAdd(&cursor[dst[e]], 1);
        ssrc[p] = src[e];
    }
}

// ------------------------- per-node softmax + aggregate --------------------
// F16OUT=1: write f16 (next layer's GEMM input). F16OUT=0: write f32 (d_out).

template <int F16OUT>
__global__ __launch_bounds__(256) void aggregate(const _Float16* __restrict__ Hh,
                                                 const float* __restrict__ si,
                                                 const float* __restrict__ sj,
                                                 const int* __restrict__ off,
                                                 const int* __restrict__ ssrc,
                                                 void* __restrict__ outv,
                                                 int n_nodes)
{
    const int v = (blockIdx.x * 256 + threadIdx.x) >> 6;   // one wave per node
    const int lane = threadIdx.x & 63;
    if (v >= n_nodes) return;

    const int e0 = off[v], e1 = off[v + 1];
    const int deg = e1 - e0;
    float4 acc = {0.f, 0.f, 0.f, 0.f};

    if (deg > 0) {
        const float siv = si[v];
        float m = -1e30f;
        for (int b = e0 + lane; b < e1; b += 64) {
            float s = siv + sj[ssrc[b]];
            s = (s >= 0.f) ? s : 0.2f * s;
            m = fmaxf(m, s);
        }
#pragma unroll
        for (int d = 32; d; d >>= 1) m = fmaxf(m, __shfl_xor(m, d));
        float den = 0.f;
        for (int b = e0 + lane; b < e1; b += 64) {
            float s = siv + sj[ssrc[b]];
            s = (s >= 0.f) ? s : 0.2f * s;
            den += __expf(s - m);
        }
#pragma unroll
        for (int d = 32; d; d >>= 1) den += __shfl_xor(den, d);
        for (int e = e0; e < e1; ++e) {
            const int s = ssrc[e];
            float sc = siv + sj[s];
            sc = (sc >= 0.f) ? sc : 0.2f * sc;
            const float wgt = __expf(sc - m);
            const f16x4 hv = *(const f16x4*)&Hh[(size_t)s * 256 + lane * 4];
            acc.x += wgt * (float)hv[0]; acc.y += wgt * (float)hv[1];
            acc.z += wgt * (float)hv[2]; acc.w += wgt * (float)hv[3];
        }
        const float inv = 1.f / (den * (float)deg);
        acc.x *= inv; acc.y *= inv; acc.z *= inv; acc.w *= inv;
    }
    float4 o;
    o.x = (acc.x > 0.f) ? acc.x : (__expf(acc.x) - 1.f);
    o.y = (acc.y > 0.f) ? acc.y : (__expf(acc.y) - 1.f);
    o.z = (acc.z > 0.f) ? acc.z : (__expf(acc.z) - 1.f);
    o.w = (acc.w > 0.f) ? acc.w : (__expf(acc.w) - 1.f);
    if (F16OUT) {
        f16x4 oh = {(_Float16)o.x, (_Float16)o.y, (_Float16)o.z, (_Float16)o.w};
        *(f16x4*)&((_Float16*)outv)[(size_t)v * 256 + lane * 4] = oh;
    } else {
        *(float4*)&((float*)outv)[(size_t)v * 256 + lane * 4] = o;
    }
}

// ---------------------------------------------------------------------------

extern "C" void kernel_launch(void* const* d_in, const int* in_sizes, int n_in,
                              void* d_out, int out_size, void* d_ws, size_t ws_size,
                              hipStream_t stream)
{
    const float* x0 = (const float*)d_in[0];
    const int*   ei = (const int*)d_in[1];      // (2,E) int32: row0=src, row1=dst
    const float* Ws[3] = {(const float*)d_in[2], (const float*)d_in[4], (const float*)d_in[6]};
    const float* as[3] = {(const float*)d_in[3], (const float*)d_in[5], (const float*)d_in[7]};
    float* out = (float*)d_out;

    const int NT = in_sizes[0] / 256;   // 32768
    const int E  = in_sizes[1] / 2;     // 262144
    const int* srcI = ei;
    const int* dstI = ei + E;

    // workspace layout (~34 MB)
    _Float16* Hh = (_Float16*)d_ws;                 // NT*256 f16
    _Float16* Xh = Hh + (size_t)NT * 256;           // NT*256 f16 (layer input)
    float* si    = (float*)(Xh + (size_t)NT * 256);
    float* sj    = si + NT;
    int* cnt     = (int*)(sj + NT);
    int* off     = cnt + NT;            // NT+1 entries
    int* cursor  = off + NT + 1;
    int* ssrc    = cursor + NT;         // E entries
    int* bsum    = ssrc + E;            // 32 entries (round up 64)
    _Float16* Wh = (_Float16*)(((uintptr_t)(bsum + 64) + 255) & ~(uintptr_t)255);

    // weight + input conversion (f32 -> f16)
    for (int l = 0; l < 3; ++l)
        convert_f16<<<32, 256, 0, stream>>>(Ws[l], Wh + (size_t)l * 65536);
    convert_f16<<<NT * 256 / 2048, 256, 0, stream>>>(x0, Xh);

    // edge preprocessing (layer-invariant)
    zero_int<<<(NT + 255) / 256, 256, 0, stream>>>(cnt, NT);
    hist_kernel<<<(E + 255) / 256, 256, 0, stream>>>(dstI, cnt, E);
    scan_part<<<NT / 1024, 1024, 0, stream>>>(cnt, off, bsum);
    scan_bsum<<<1, 64, 0, stream>>>(bsum, NT / 1024);
    scan_add<<<NT / 1024, 1024, 0, stream>>>(bsum, off, cursor, NT, E);
    scatter_kernel<<<(E + 255) / 256, 256, 0, stream>>>(srcI, dstI, cursor, ssrc, E);

    for (int l = 0; l < 3; ++l) {
        gemm_f16<<<NT / 64, 256, 0, stream>>>(Xh, Wh + (size_t)l * 65536, as[l], Hh, si, sj);
        if (l < 2)
            aggregate<1><<<NT / 4, 256, 0, stream>>>(Hh, si, sj, off, ssrc, (void*)Xh, NT);
        else
            aggregate<0><<<NT / 4, 256, 0, stream>>>(Hh, si, sj, off, ssrc, (void*)out, NT);
    }
}

// Round 8
// 266.463 us; speedup vs baseline: 1.9635x; 1.2182x over previous
//
#include <hip/hip_runtime.h>
#include <math.h>
#include <stdint.h>

// ---------------------------------------------------------------------------
// SpatialDecoder: 3x { h = x @ W^T ; GAT edge softmax over dst ; mean ; ELU }
// NT = 32768 nodes, C = H = 256, E = 262144 edges.
// This round: single-pass aggregate. One wave per node: edge-parallel score +
// softmax (lane = edge, deg<=64 fast path), then column-parallel gather with
// x4 unrolled row loads (4 outstanding vmem) and readlane-broadcast weights.
// ---------------------------------------------------------------------------

typedef float f32x4 __attribute__((ext_vector_type(4)));
typedef _Float16 f16x8 __attribute__((ext_vector_type(8)));
typedef _Float16 f16x4 __attribute__((ext_vector_type(4)));

#define LDSPAD 40   // f16 elements per LDS row slot (80B, 16B-aligned, <=2-way)

// ------------------------- f32 -> f16 conversion ---------------------------

__global__ __launch_bounds__(256) void convert_f16(const float* __restrict__ src,
                                                   _Float16* __restrict__ dstp)
{
    const int i = (blockIdx.x * 256 + threadIdx.x) * 8;
    float4 a = *(const float4*)&src[i];
    float4 b = *(const float4*)&src[i + 4];
    f16x8 o = {(_Float16)a.x, (_Float16)a.y, (_Float16)a.z, (_Float16)a.w,
               (_Float16)b.x, (_Float16)b.y, (_Float16)b.z, (_Float16)b.w};
    *(f16x8*)&dstp[i] = o;
}

// ------------------------- fp16 MFMA GEMM + row dots -----------------------
// Hout(M,256) = X(M,256) @ Wh(256,256)^T ; si = Hout@a[:256], sj = Hout@a[256:]

__global__ __launch_bounds__(256) void gemm_f16(const _Float16* __restrict__ X,
                                                const _Float16* __restrict__ Wh,
                                                const float* __restrict__ avec,
                                                _Float16* __restrict__ Hout,
                                                float* __restrict__ si,
                                                float* __restrict__ sj)
{
    __shared__ __align__(16) unsigned char smem[64 * LDSPAD * 2 + 256 * LDSPAD * 2];
    _Float16* Xs = (_Float16*)smem;                         // [64][LDSPAD]
    _Float16* Wl = (_Float16*)(smem + 64 * LDSPAD * 2);     // [256][LDSPAD]
    float*    Es = (float*)smem;                            // epilogue [16][260]

    const int tid  = threadIdx.x;
    const int lane = tid & 63;
    const int w    = tid >> 6;        // wave id = n-chunk (64 cols each)
    const int ln   = lane & 15;
    const int kq   = lane >> 4;
    const int m0   = blockIdx.x * 64;

    f32x4 acc[4][4] = {};

    const int sr = tid >> 2;          // X staging row 0..63
    const int sc = tid & 3;           // X staging chunk (8 f16 each)
    const _Float16* Xrow = X  + (size_t)(m0 + sr) * 256;
    const _Float16* Wrow = Wh + (size_t)tid * 256;

    for (int k0 = 0; k0 < 256; k0 += 32) {
        // stage X tile (64x32 f16) — one 16B copy per thread
        f16x8 xv = *(const f16x8*)&Xrow[k0 + sc * 8];
        *(f16x8*)&Xs[sr * LDSPAD + sc * 8] = xv;
        // stage W tile (256x32 f16)
        f16x8 w0 = *(const f16x8*)&Wrow[k0 + 0];
        f16x8 w1 = *(const f16x8*)&Wrow[k0 + 8];
        f16x8 w2 = *(const f16x8*)&Wrow[k0 + 16];
        f16x8 w3 = *(const f16x8*)&Wrow[k0 + 24];
        *(f16x8*)&Wl[tid * LDSPAD + 0]  = w0;
        *(f16x8*)&Wl[tid * LDSPAD + 8]  = w1;
        *(f16x8*)&Wl[tid * LDSPAD + 16] = w2;
        *(f16x8*)&Wl[tid * LDSPAD + 24] = w3;
        __syncthreads();

        f16x8 af[4], bf[4];
#pragma unroll
        for (int i = 0; i < 4; ++i)
            af[i] = *(const f16x8*)&Xs[(i * 16 + ln) * LDSPAD + kq * 8];
#pragma unroll
        for (int j = 0; j < 4; ++j)
            bf[j] = *(const f16x8*)&Wl[(w * 64 + j * 16 + ln) * LDSPAD + kq * 8];
#pragma unroll
        for (int i = 0; i < 4; ++i)
#pragma unroll
            for (int j = 0; j < 4; ++j)
                acc[i][j] = __builtin_amdgcn_mfma_f32_16x16x32_f16(af[i], bf[j], acc[i][j], 0, 0, 0);
        __syncthreads();
    }

    // Epilogue: LDS-transpose per 16-row group, coalesced f16 store + fused dots.
    const int er = tid >> 4;          // row in 16-group
    const int ec = tid & 15;          // col-quad index
    for (int i = 0; i < 4; ++i) {
#pragma unroll
        for (int j = 0; j < 4; ++j) {
            const int col = w * 64 + j * 16 + ln;
#pragma unroll
            for (int q = 0; q < 4; ++q)
                Es[(kq * 4 + q) * 260 + col] = acc[i][j][q];
        }
        __syncthreads();
        const int grow = m0 + i * 16 + er;
        float d0 = 0.f, d1 = 0.f;
#pragma unroll
        for (int c4 = 0; c4 < 4; ++c4) {
            const int col = ec * 4 + c4 * 64;
            f32x4 v  = *(const f32x4*)&Es[er * 260 + col];
            f16x4 hv = {(_Float16)v[0], (_Float16)v[1], (_Float16)v[2], (_Float16)v[3]};
            *(f16x4*)&Hout[(size_t)grow * 256 + col] = hv;
            f32x4 al = *(const f32x4*)&avec[col];
            f32x4 ah = *(const f32x4*)&avec[256 + col];
            d0 += v[0] * al[0] + v[1] * al[1] + v[2] * al[2] + v[3] * al[3];
            d1 += v[0] * ah[0] + v[1] * ah[1] + v[2] * ah[2] + v[3] * ah[3];
        }
#pragma unroll
        for (int d = 8; d; d >>= 1) {
            d0 += __shfl_xor(d0, d);
            d1 += __shfl_xor(d1, d);
        }
        if (ec == 0) { si[grow] = d0; sj[grow] = d1; }
        __syncthreads();
    }
}

// ------------------------- edge preprocessing ------------------------------

__global__ void zero_int(int* p, int n)
{
    int i = blockIdx.x * blockDim.x + threadIdx.x;
    if (i < n) p[i] = 0;
}

__global__ void hist_kernel(const int* __restrict__ dst, int* __restrict__ cnt, int E)
{
    int e = blockIdx.x * blockDim.x + threadIdx.x;
    if (e < E) atomicAdd(&cnt[dst[e]], 1);
}

__global__ __launch_bounds__(1024) void scan_part(const int* __restrict__ cnt,
                                                  int* __restrict__ off,
                                                  int* __restrict__ bsum)
{
    __shared__ int buf[1024];
    const int tid = threadIdx.x;
    const int g = blockIdx.x * 1024 + tid;
    int v = cnt[g];
    buf[tid] = v;
    __syncthreads();
#pragma unroll
    for (int d = 1; d < 1024; d <<= 1) {
        int t = (tid >= d) ? buf[tid - d] : 0;
        __syncthreads();
        buf[tid] += t;
        __syncthreads();
    }
    off[g] = buf[tid] - v;                      // local exclusive
    if (tid == 1023) bsum[blockIdx.x] = buf[1023];
}

__global__ void scan_bsum(int* bsum, int nb)
{
    __shared__ int b[64];
    const int tid = threadIdx.x;                // 64 threads
    b[tid] = (tid < nb) ? bsum[tid] : 0;
    __syncthreads();
    if (tid == 0) {
        int a = 0;
        for (int i = 0; i < nb; ++i) { int t = b[i]; b[i] = a; a += t; }
    }
    __syncthreads();
    if (tid < nb) bsum[tid] = b[tid];
}

__global__ __launch_bounds__(1024) void scan_add(const int* __restrict__ bsum,
                                                 int* __restrict__ off,
                                                 int* __restrict__ cursor,
                                                 int NT, int E)
{
    const int tid = threadIdx.x;
    const int g = blockIdx.x * 1024 + tid;
    int v = off[g] + bsum[blockIdx.x];
    off[g] = v;
    cursor[g] = v;
    if (g == 0) off[NT] = E;
}

__global__ void scatter_kernel(const int* __restrict__ src,
                               const int* __restrict__ dst,
                               int* __restrict__ cursor,
                               int* __restrict__ ssrc, int E)
{
    int e = blockIdx.x * blockDim.x + threadIdx.x;
    if (e < E) {
        int p = atomicAdd(&cursor[dst[e]], 1);
        ssrc[p] = src[e];
    }
}

// ------------------------- per-node softmax + aggregate --------------------
// One wave per node. Fast path (deg<=64): lane=edge score+softmax in one pass,
// then x4-unrolled row gather with readlane-broadcast (src,weight).
// F16OUT=1: write f16 (next layer's GEMM input). F16OUT=0: write f32 (d_out).

__device__ __forceinline__ float bcast_f(float x, int l)
{
    return __uint_as_float(__builtin_amdgcn_readlane(__float_as_uint(x), l));
}

template <int F16OUT>
__global__ __launch_bounds__(256) void aggregate(const _Float16* __restrict__ Hh,
                                                 const float* __restrict__ si,
                                                 const float* __restrict__ sj,
                                                 const int* __restrict__ off,
                                                 const int* __restrict__ ssrc,
                                                 void* __restrict__ outv,
                                                 int n_nodes)
{
    const int v = (blockIdx.x * 256 + threadIdx.x) >> 6;   // one wave per node
    const int lane = threadIdx.x & 63;
    if (v >= n_nodes) return;

    const int e0 = off[v], e1 = off[v + 1];
    const int deg = e1 - e0;
    f32x4 acc = {0.f, 0.f, 0.f, 0.f};

    if (deg > 0 && deg <= 64) {
        const float siv = si[v];
        // edge-parallel score: lane l owns edge e0+l
        const int idx = e0 + lane;
        const bool on = idx < e1;
        int s = 0;
        float scv = -1e30f;
        if (on) {
            s = ssrc[idx];
            float t = siv + sj[s];
            scv = (t >= 0.f) ? t : 0.2f * t;
        }
        float m = scv;
#pragma unroll
        for (int d = 32; d; d >>= 1) m = fmaxf(m, __shfl_xor(m, d));
        float wv = on ? __expf(scv - m) : 0.f;
        float den = wv;
#pragma unroll
        for (int d = 32; d; d >>= 1) den += __shfl_xor(den, d);

        // column-parallel gather: lane covers cols [lane*4, lane*4+4)
        const int c4 = lane * 4;
        for (int eo = 0; eo < deg; eo += 4) {
            const int l1 = (eo + 1 < 63) ? eo + 1 : 63;
            const int l2 = (eo + 2 < 63) ? eo + 2 : 63;
            const int l3 = (eo + 3 < 63) ? eo + 3 : 63;
            const int s0 = __builtin_amdgcn_readlane(s, eo);
            const int s1 = __builtin_amdgcn_readlane(s, l1);
            const int s2 = __builtin_amdgcn_readlane(s, l2);
            const int s3 = __builtin_amdgcn_readlane(s, l3);
            const float w0 = bcast_f(wv, eo);
            const float w1 = bcast_f(wv, l1);
            const float w2 = bcast_f(wv, l2);
            const float w3 = bcast_f(wv, l3);
            // 4 independent 512B row loads in flight
            const f16x4 v0 = *(const f16x4*)&Hh[(size_t)s0 * 256 + c4];
            const f16x4 v1 = *(const f16x4*)&Hh[(size_t)s1 * 256 + c4];
            const f16x4 v2 = *(const f16x4*)&Hh[(size_t)s2 * 256 + c4];
            const f16x4 v3 = *(const f16x4*)&Hh[(size_t)s3 * 256 + c4];
#pragma unroll
            for (int q = 0; q < 4; ++q)
                acc[q] += w0 * (float)v0[q] + w1 * (float)v1[q]
                        + w2 * (float)v2[q] + w3 * (float)v3[q];
        }
        const float inv = 1.f / (den * (float)deg);
#pragma unroll
        for (int q = 0; q < 4; ++q) acc[q] *= inv;
    } else if (deg > 64) {
        // generic fallback (rare): 3-pass lane-strided
        const float siv = si[v];
        float m = -1e30f;
        for (int b = e0 + lane; b < e1; b += 64) {
            float t = siv + sj[ssrc[b]];
            t = (t >= 0.f) ? t : 0.2f * t;
            m = fmaxf(m, t);
        }
#pragma unroll
        for (int d = 32; d; d >>= 1) m = fmaxf(m, __shfl_xor(m, d));
        float den = 0.f;
        for (int b = e0 + lane; b < e1; b += 64) {
            float t = siv + sj[ssrc[b]];
            t = (t >= 0.f) ? t : 0.2f * t;
            den += __expf(t - m);
        }
#pragma unroll
        for (int d = 32; d; d >>= 1) den += __shfl_xor(den, d);
        for (int e = e0; e < e1; ++e) {
            const int s = ssrc[e];
            float t = siv + sj[s];
            t = (t >= 0.f) ? t : 0.2f * t;
            const float wgt = __expf(t - m);
            const f16x4 hv = *(const f16x4*)&Hh[(size_t)s * 256 + lane * 4];
#pragma unroll
            for (int q = 0; q < 4; ++q) acc[q] += wgt * (float)hv[q];
        }
        const float inv = 1.f / (den * (float)deg);
#pragma unroll
        for (int q = 0; q < 4; ++q) acc[q] *= inv;
    }

    // ELU + store
    float4 o;
    o.x = (acc[0] > 0.f) ? acc[0] : (__expf(acc[0]) - 1.f);
    o.y = (acc[1] > 0.f) ? acc[1] : (__expf(acc[1]) - 1.f);
    o.z = (acc[2] > 0.f) ? acc[2] : (__expf(acc[2]) - 1.f);
    o.w = (acc[3] > 0.f) ? acc[3] : (__expf(acc[3]) - 1.f);
    if (F16OUT) {
        f16x4 oh = {(_Float16)o.x, (_Float16)o.y, (_Float16)o.z, (_Float16)o.w};
        *(f16x4*)&((_Float16*)outv)[(size_t)v * 256 + lane * 4] = oh;
    } else {
        *(float4*)&((float*)outv)[(size_t)v * 256 + lane * 4] = o;
    }
}

// ---------------------------------------------------------------------------

extern "C" void kernel_launch(void* const* d_in, const int* in_sizes, int n_in,
                              void* d_out, int out_size, void* d_ws, size_t ws_size,
                              hipStream_t stream)
{
    const float* x0 = (const float*)d_in[0];
    const int*   ei = (const int*)d_in[1];      // (2,E) int32: row0=src, row1=dst
    const float* Ws[3] = {(const float*)d_in[2], (const float*)d_in[4], (const float*)d_in[6]};
    const float* as[3] = {(const float*)d_in[3], (const float*)d_in[5], (const float*)d_in[7]};
    float* out = (float*)d_out;

    const int NT = in_sizes[0] / 256;   // 32768
    const int E  = in_sizes[1] / 2;     // 262144
    const int* srcI = ei;
    const int* dstI = ei + E;

    // workspace layout (~34 MB)
    _Float16* Hh = (_Float16*)d_ws;                 // NT*256 f16
    _Float16* Xh = Hh + (size_t)NT * 256;           // NT*256 f16 (layer input)
    float* si    = (float*)(Xh + (size_t)NT * 256);
    float* sj    = si + NT;
    int* cnt     = (int*)(sj + NT);
    int* off     = cnt + NT;            // NT+1 entries
    int* cursor  = off + NT + 1;
    int* ssrc    = cursor + NT;         // E entries
    int* bsum    = ssrc + E;            // 32 entries (round up 64)
    _Float16* Wh = (_Float16*)(((uintptr_t)(bsum + 64) + 255) & ~(uintptr_t)255);

    // weight + input conversion (f32 -> f16)
    for (int l = 0; l < 3; ++l)
        convert_f16<<<32, 256, 0, stream>>>(Ws[l], Wh + (size_t)l * 65536);
    convert_f16<<<NT * 256 / 2048, 256, 0, stream>>>(x0, Xh);

    // edge preprocessing (layer-invariant)
    zero_int<<<(NT + 255) / 256, 256, 0, stream>>>(cnt, NT);
    hist_kernel<<<(E + 255) / 256, 256, 0, stream>>>(dstI, cnt, E);
    scan_part<<<NT / 1024, 1024, 0, stream>>>(cnt, off, bsum);
    scan_bsum<<<1, 64, 0, stream>>>(bsum, NT / 1024);
    scan_add<<<NT / 1024, 1024, 0, stream>>>(bsum, off, cursor, NT, E);
    scatter_kernel<<<(E + 255) / 256, 256, 0, stream>>>(srcI, dstI, cursor, ssrc, E);

    for (int l = 0; l < 3; ++l) {
        gemm_f16<<<NT / 64, 256, 0, stream>>>(Xh, Wh + (size_t)l * 65536, as[l], Hh, si, sj);
        if (l < 2)
            aggregate<1><<<NT / 4, 256, 0, stream>>>(Hh, si, sj, off, ssrc, (void*)Xh, NT);
        else
            aggregate<0><<<NT / 4, 256, 0, stream>>>(Hh, si, sj, off, ssrc, (void*)out, NT);
    }
}